// Round 1
// baseline (472.191 us; speedup 1.0000x reference)
//
#include <hip/hip_runtime.h>
#include <stdint.h>

typedef unsigned short u16;
typedef __bf16 bf16;
typedef bf16 bf16x8 __attribute__((ext_vector_type(8)));
typedef float f32x4 __attribute__((ext_vector_type(4)));
typedef uint32_t u32x4 __attribute__((ext_vector_type(4)));

// ---- constants: B=4, S=4096, D_IN=768, D_OUT=128 ----
#define S_LEN 4096
#define D_IN 768
#define D_OUT 128
#define NB 4
#define M_TOTAL (NB * S_LEN) // 16384

static __device__ __forceinline__ u16 f2bf(float f) {
    union { float f; uint32_t u; } c; c.f = f;
    return (u16)((c.u + 0x7FFFu + ((c.u >> 16) & 1u)) >> 16);
}

static __device__ __forceinline__ bf16x8 ld8(const u16* p) {
    union { u32x4 v; bf16x8 b; } c;
    c.v = *reinterpret_cast<const u32x4*>(p);
    return c.b;
}

static __device__ __forceinline__ f32x4 mfma16(bf16x8 a, bf16x8 b, f32x4 c) {
    return __builtin_amdgcn_mfma_f32_16x16x32_bf16(a, b, c, 0, 0, 0);
}

// ---------------- Kernel 1: W -> W^T bf16  (Wt[w][n][k]) ----------------
__global__ void wt_kernel(const float* __restrict__ Wq, const float* __restrict__ Wk,
                          const float* __restrict__ Wv, u16* __restrict__ Wt) {
    int t = blockIdx.x * 256 + threadIdx.x; // 3*128*768 total, exact multiple
    int w = t / (D_OUT * D_IN);
    int rem = t % (D_OUT * D_IN);
    int n = rem / D_IN;
    int k = rem % D_IN;
    const float* W = (w == 0) ? Wq : (w == 1) ? Wk : Wv;
    Wt[t] = f2bf(W[k * D_OUT + n]);
}

// ---------------- Kernel 2: QKV projection GEMM ----------------
// grid(256, 3), block 256 (4 waves x 16 rows). Q,K row-major bf16; V stored transposed.
__global__ __launch_bounds__(256) void qkv_kernel(const float* __restrict__ x, const u16* __restrict__ Wt,
                                                  u16* __restrict__ Qb, u16* __restrict__ Kb,
                                                  u16* __restrict__ Vt) {
    const int wave = threadIdx.x >> 6, lane = threadIdx.x & 63;
    const int r = lane & 15, g = lane >> 4;
    const int m0 = blockIdx.x * 64 + wave * 16;
    const int y = blockIdx.y;
    const u16* wt = Wt + y * (D_OUT * D_IN);

    f32x4 acc[8];
#pragma unroll
    for (int f = 0; f < 8; ++f) acc[f] = f32x4{0.f, 0.f, 0.f, 0.f};

    const float* ap0 = x + (size_t)(m0 + r) * D_IN;
    for (int kk = 0; kk < D_IN / 32; ++kk) {
        const int kbase = kk * 32 + 8 * g;
        const float* ap = ap0 + kbase;
        float4 a0 = *reinterpret_cast<const float4*>(ap);
        float4 a1 = *reinterpret_cast<const float4*>(ap + 4);
        union { u16 u[8]; bf16x8 b; } af;
        af.u[0] = f2bf(a0.x); af.u[1] = f2bf(a0.y); af.u[2] = f2bf(a0.z); af.u[3] = f2bf(a0.w);
        af.u[4] = f2bf(a1.x); af.u[5] = f2bf(a1.y); af.u[6] = f2bf(a1.z); af.u[7] = f2bf(a1.w);
#pragma unroll
        for (int f = 0; f < 8; ++f) {
            bf16x8 bf = ld8(wt + (size_t)(f * 16 + r) * D_IN + kbase);
            acc[f] = mfma16(af.b, bf, acc[f]);
        }
    }

    if (y < 2) {
        u16* outp = (y == 0) ? Qb : Kb;
#pragma unroll
        for (int f = 0; f < 8; ++f)
#pragma unroll
            for (int i = 0; i < 4; ++i)
                outp[(size_t)(m0 + 4 * g + i) * D_OUT + f * 16 + r] = f2bf(acc[f][i]);
    } else {
        // V^T: Vt[b][d][pos], b = mrow>>12, pos = mrow&4095
#pragma unroll
        for (int f = 0; f < 8; ++f)
#pragma unroll
            for (int i = 0; i < 4; ++i) {
                int mrow = m0 + 4 * g + i;
                Vt[((size_t)((mrow >> 12) * D_OUT + f * 16 + r)) * S_LEN + (mrow & 4095)] = f2bf(acc[f][i]);
            }
    }
}

// ---------------- Kernel 3: causal flash attention ----------------
// grid(256, 4), block 64 (one wave per 16-row Q tile). tile = 255 - blockIdx.x (longest first).
__global__ __launch_bounds__(64) void attn_kernel(const u16* __restrict__ Qb, const u16* __restrict__ Kb,
                                                  const u16* __restrict__ Vt, float* __restrict__ out) {
    __shared__ u16 plds[16 * 72]; // P transpose buffer, row stride 72 bf16 = 144B (16B aligned)
    const int lane = threadIdx.x & 63;
    const int r = lane & 15, g = lane >> 4;
    const int b = blockIdx.y;
    const int tile = 255 - (int)blockIdx.x;
    const int q0 = tile << 4;

    // Q fragments (A layout): row = q0 + (l&15), k = kk*32 + 8*(l>>4) + j
    const u16* Qp = Qb + ((size_t)(b * S_LEN + q0 + r)) * D_OUT + 8 * g;
    bf16x8 qf[4];
#pragma unroll
    for (int kk = 0; kk < 4; ++kk) qf[kk] = ld8(Qp + kk * 32);

    f32x4 o[8];
#pragma unroll
    for (int f = 0; f < 8; ++f) o[f] = f32x4{0.f, 0.f, 0.f, 0.f};
    float m_[4], l_[4];
#pragma unroll
    for (int i = 0; i < 4; ++i) { m_[i] = -1e30f; l_[i] = 0.f; }

    const u16* Kp = Kb + (size_t)b * S_LEN * D_OUT;
    const u16* Vp = Vt + (size_t)b * D_OUT * S_LEN;
    const int kend = q0 + 16;
    const float sc = 0.08838834764831845f;      // 1/sqrt(128)
    const float LOG2E = 1.4426950408889634f;

    for (int k0 = 0; k0 < kend; k0 += 64) {
        // ---- S = Q K^T (16 x 64) ----
        f32x4 s[4];
#pragma unroll
        for (int f = 0; f < 4; ++f) s[f] = f32x4{0.f, 0.f, 0.f, 0.f};
#pragma unroll
        for (int kk = 0; kk < 4; ++kk) {
            const u16* kp = Kp + (size_t)(k0 + r) * D_OUT + kk * 32 + 8 * g;
#pragma unroll
            for (int f = 0; f < 4; ++f) {
                bf16x8 kf = ld8(kp + (size_t)f * 16 * D_OUT);
                s[f] = mfma16(qf[kk], kf, s[f]);
            }
        }
        // ---- scale + causal mask + row max ----
        float pm[4] = {-1e30f, -1e30f, -1e30f, -1e30f};
        const bool last = (k0 + 64 >= kend);
        if (last) {
#pragma unroll
            for (int f = 0; f < 4; ++f)
#pragma unroll
                for (int i = 0; i < 4; ++i) {
                    float v = s[f][i] * sc;
                    int kc = k0 + f * 16 + r;
                    int qr = q0 + 4 * g + i;
                    if (kc > qr) v = -1e30f;
                    s[f][i] = v;
                    pm[i] = fmaxf(pm[i], v);
                }
        } else {
#pragma unroll
            for (int f = 0; f < 4; ++f)
#pragma unroll
                for (int i = 0; i < 4; ++i) {
                    float v = s[f][i] * sc;
                    s[f][i] = v;
                    pm[i] = fmaxf(pm[i], v);
                }
        }
#pragma unroll
        for (int mk = 1; mk < 16; mk <<= 1)
#pragma unroll
            for (int i = 0; i < 4; ++i) pm[i] = fmaxf(pm[i], __shfl_xor(pm[i], mk, 64));

        // ---- online softmax update ----
        float al[4], rs[4];
#pragma unroll
        for (int i = 0; i < 4; ++i) {
            float mn = fmaxf(m_[i], pm[i]);
            al[i] = exp2f((m_[i] - mn) * LOG2E);
            m_[i] = mn;
            rs[i] = 0.f;
        }
#pragma unroll
        for (int f = 0; f < 4; ++f)
#pragma unroll
            for (int i = 0; i < 4; ++i) {
                float p = exp2f((s[f][i] - m_[i]) * LOG2E);
                s[f][i] = p;
                rs[i] += p;
            }
#pragma unroll
        for (int mk = 1; mk < 16; mk <<= 1)
#pragma unroll
            for (int i = 0; i < 4; ++i) rs[i] += __shfl_xor(rs[i], mk, 64);
#pragma unroll
        for (int i = 0; i < 4; ++i) l_[i] = l_[i] * al[i] + rs[i];
#pragma unroll
        for (int f = 0; f < 8; ++f)
#pragma unroll
            for (int i = 0; i < 4; ++i) o[f][i] *= al[i];

        // ---- P: D layout -> A layout through LDS ----
#pragma unroll
        for (int f = 0; f < 4; ++f)
#pragma unroll
            for (int i = 0; i < 4; ++i)
                plds[(4 * g + i) * 72 + f * 16 + r] = f2bf(s[f][i]);
        asm volatile("s_waitcnt lgkmcnt(0)" ::: "memory");

        // ---- O += P V ----
#pragma unroll
        for (int kk2 = 0; kk2 < 2; ++kk2) {
            bf16x8 pf = ld8(&plds[r * 72 + kk2 * 32 + 8 * g]);
#pragma unroll
            for (int f = 0; f < 8; ++f) {
                bf16x8 vf = ld8(Vp + (size_t)(f * 16 + r) * S_LEN + k0 + kk2 * 32 + 8 * g);
                o[f] = mfma16(pf, vf, o[f]);
            }
        }
    }

    // ---- epilogue ----
    float inv[4];
#pragma unroll
    for (int i = 0; i < 4; ++i) inv[i] = 1.0f / l_[i];
    float* op = out + ((size_t)(b * S_LEN + q0)) * D_OUT;
#pragma unroll
    for (int f = 0; f < 8; ++f)
#pragma unroll
        for (int i = 0; i < 4; ++i)
            op[(size_t)(4 * g + i) * D_OUT + f * 16 + r] = o[f][i] * inv[i];
}

extern "C" void kernel_launch(void* const* d_in, const int* in_sizes, int n_in,
                              void* d_out, int out_size, void* d_ws, size_t ws_size,
                              hipStream_t stream) {
    const float* x  = (const float*)d_in[0];
    const float* Wq = (const float*)d_in[1];
    const float* Wk = (const float*)d_in[2];
    const float* Wv = (const float*)d_in[3];
    float* out = (float*)d_out;

    // workspace layout (bf16 ushorts): Q | K | V^T | W^T  = ~12.6 MiB
    u16* Qb = (u16*)d_ws;
    u16* Kb = Qb + (size_t)M_TOTAL * D_OUT;
    u16* Vt = Kb + (size_t)M_TOTAL * D_OUT;
    u16* Wt = Vt + (size_t)M_TOTAL * D_OUT;

    wt_kernel<<<(3 * D_OUT * D_IN) / 256, 256, 0, stream>>>(Wq, Wk, Wv, Wt);
    qkv_kernel<<<dim3(M_TOTAL / 64, 3), 256, 0, stream>>>(x, Wt, Qb, Kb, Vt);
    attn_kernel<<<dim3(S_LEN / 16, NB), 64, 0, stream>>>(Qb, Kb, Vt, out);
}

// Round 2
// 270.191 us; speedup vs baseline: 1.7476x; 1.7476x over previous
//
#include <hip/hip_runtime.h>
#include <stdint.h>

typedef unsigned short u16;
typedef __bf16 bf16;
typedef bf16 bf16x8 __attribute__((ext_vector_type(8)));
typedef float f32x4 __attribute__((ext_vector_type(4)));
typedef uint32_t u32x4 __attribute__((ext_vector_type(4)));

// ---- constants: B=4, S=4096, D_IN=768, D_OUT=128 ----
#define S_LEN 4096
#define D_IN 768
#define D_OUT 128
#define NB 4
#define M_TOTAL (NB * S_LEN) // 16384
#define NW 4                 // waves per attention block (KV-split factor)

static __device__ __forceinline__ u16 f2bf(float f) {
    union { float f; uint32_t u; } c; c.f = f;
    return (u16)((c.u + 0x7FFFu + ((c.u >> 16) & 1u)) >> 16);
}

static __device__ __forceinline__ bf16x8 ld8(const u16* p) {
    union { u32x4 v; bf16x8 b; } c;
    c.v = *reinterpret_cast<const u32x4*>(p);
    return c.b;
}

static __device__ __forceinline__ f32x4 mfma16(bf16x8 a, bf16x8 b, f32x4 c) {
    return __builtin_amdgcn_mfma_f32_16x16x32_bf16(a, b, c, 0, 0, 0);
}

// ---------------- Kernel 1: W -> W^T bf16  (Wt[w][n][k]) ----------------
__global__ void wt_kernel(const float* __restrict__ Wq, const float* __restrict__ Wk,
                          const float* __restrict__ Wv, u16* __restrict__ Wt) {
    int t = blockIdx.x * 256 + threadIdx.x; // 3*128*768 total, exact multiple
    int w = t / (D_OUT * D_IN);
    int rem = t % (D_OUT * D_IN);
    int n = rem / D_IN;
    int k = rem % D_IN;
    const float* W = (w == 0) ? Wq : (w == 1) ? Wk : Wv;
    Wt[t] = f2bf(W[k * D_OUT + n]);
}

// ---------------- Kernel 2: QKV projection GEMM ----------------
// grid(256, 3), block 256 (4 waves x 16 rows). Q,K row-major bf16; V stored transposed.
__global__ __launch_bounds__(256) void qkv_kernel(const float* __restrict__ x, const u16* __restrict__ Wt,
                                                  u16* __restrict__ Qb, u16* __restrict__ Kb,
                                                  u16* __restrict__ Vt) {
    const int wave = threadIdx.x >> 6, lane = threadIdx.x & 63;
    const int r = lane & 15, g = lane >> 4;
    const int m0 = blockIdx.x * 64 + wave * 16;
    const int y = blockIdx.y;
    const u16* wt = Wt + y * (D_OUT * D_IN);

    f32x4 acc[8];
#pragma unroll
    for (int f = 0; f < 8; ++f) acc[f] = f32x4{0.f, 0.f, 0.f, 0.f};

    const float* ap0 = x + (size_t)(m0 + r) * D_IN;
    for (int kk = 0; kk < D_IN / 32; ++kk) {
        const int kbase = kk * 32 + 8 * g;
        const float* ap = ap0 + kbase;
        float4 a0 = *reinterpret_cast<const float4*>(ap);
        float4 a1 = *reinterpret_cast<const float4*>(ap + 4);
        union { u16 u[8]; bf16x8 b; } af;
        af.u[0] = f2bf(a0.x); af.u[1] = f2bf(a0.y); af.u[2] = f2bf(a0.z); af.u[3] = f2bf(a0.w);
        af.u[4] = f2bf(a1.x); af.u[5] = f2bf(a1.y); af.u[6] = f2bf(a1.z); af.u[7] = f2bf(a1.w);
#pragma unroll
        for (int f = 0; f < 8; ++f) {
            bf16x8 bf = ld8(wt + (size_t)(f * 16 + r) * D_IN + kbase);
            acc[f] = mfma16(af.b, bf, acc[f]);
        }
    }

    if (y < 2) {
        u16* outp = (y == 0) ? Qb : Kb;
#pragma unroll
        for (int f = 0; f < 8; ++f)
#pragma unroll
            for (int i = 0; i < 4; ++i)
                outp[(size_t)(m0 + 4 * g + i) * D_OUT + f * 16 + r] = f2bf(acc[f][i]);
    } else {
        // V^T: Vt[b][d][pos], b = mrow>>12, pos = mrow&4095
#pragma unroll
        for (int f = 0; f < 8; ++f)
#pragma unroll
            for (int i = 0; i < 4; ++i) {
                int mrow = m0 + 4 * g + i;
                Vt[((size_t)((mrow >> 12) * D_OUT + f * 16 + r)) * S_LEN + (mrow & 4095)] = f2bf(acc[f][i]);
            }
    }
}

// ---------------- Kernel 3: causal flash attention ----------------
// grid(256, 4), block 256 = 4 waves. One 16-row Q tile per BLOCK; waves interleave
// KV tiles stride-NW, each keeps private (m,l,O~); LDS combine at the end.
__global__ __launch_bounds__(256) void attn_kernel(const u16* __restrict__ Qb, const u16* __restrict__ Kb,
                                                   const u16* __restrict__ Vt, float* __restrict__ out) {
    __shared__ u16 plds[NW][16 * 72]; // per-wave P transpose buffer (row stride 72 bf16)
    __shared__ float m_s[NW][16], l_s[NW][16];
    __shared__ float o_acc[16][128];

    const int wave = threadIdx.x >> 6, lane = threadIdx.x & 63;
    const int r = lane & 15, g = lane >> 4;
    const int b = blockIdx.y;
    const int tile = 255 - (int)blockIdx.x; // LPT: longest causal range first
    const int q0 = tile << 4;

    // Q fragments (A layout): row = q0 + (l&15), k = kk*32 + 8*(l>>4) + j
    const u16* Qp = Qb + ((size_t)(b * S_LEN + q0 + r)) * D_OUT + 8 * g;
    bf16x8 qf[4];
#pragma unroll
    for (int kk = 0; kk < 4; ++kk) qf[kk] = ld8(Qp + kk * 32);

    f32x4 o[8];
#pragma unroll
    for (int f = 0; f < 8; ++f) o[f] = f32x4{0.f, 0.f, 0.f, 0.f};
    float m_[4], l_[4];
#pragma unroll
    for (int i = 0; i < 4; ++i) { m_[i] = -1e30f; l_[i] = 0.f; }

    const u16* Kp = Kb + (size_t)b * S_LEN * D_OUT;
    const u16* Vp = Vt + (size_t)b * D_OUT * S_LEN;
    const int kend = q0 + 16;
    const float sc = 0.08838834764831845f;      // 1/sqrt(128)
    const float LOG2E = 1.4426950408889634f;

    for (int k0 = wave * 64; k0 < kend; k0 += NW * 64) {
        // ---- S = Q K^T (16 x 64) ----
        f32x4 s[4];
#pragma unroll
        for (int f = 0; f < 4; ++f) s[f] = f32x4{0.f, 0.f, 0.f, 0.f};
#pragma unroll
        for (int kk = 0; kk < 4; ++kk) {
            const u16* kp = Kp + (size_t)(k0 + r) * D_OUT + kk * 32 + 8 * g;
#pragma unroll
            for (int f = 0; f < 4; ++f) {
                bf16x8 kf = ld8(kp + (size_t)f * 16 * D_OUT);
                s[f] = mfma16(qf[kk], kf, s[f]);
            }
        }
        // ---- scale + causal mask + row max ----
        float pm[4] = {-1e30f, -1e30f, -1e30f, -1e30f};
        const bool last = (k0 + 64 >= kend);
        if (last) {
#pragma unroll
            for (int f = 0; f < 4; ++f)
#pragma unroll
                for (int i = 0; i < 4; ++i) {
                    float v = s[f][i] * sc;
                    int kc = k0 + f * 16 + r;
                    int qr = q0 + 4 * g + i;
                    if (kc > qr) v = -1e30f;
                    s[f][i] = v;
                    pm[i] = fmaxf(pm[i], v);
                }
        } else {
#pragma unroll
            for (int f = 0; f < 4; ++f)
#pragma unroll
                for (int i = 0; i < 4; ++i) {
                    float v = s[f][i] * sc;
                    s[f][i] = v;
                    pm[i] = fmaxf(pm[i], v);
                }
        }
#pragma unroll
        for (int mk = 1; mk < 16; mk <<= 1)
#pragma unroll
            for (int i = 0; i < 4; ++i) pm[i] = fmaxf(pm[i], __shfl_xor(pm[i], mk, 64));

        // ---- online softmax update ----
        float al[4], rs[4];
#pragma unroll
        for (int i = 0; i < 4; ++i) {
            float mn = fmaxf(m_[i], pm[i]);
            al[i] = exp2f((m_[i] - mn) * LOG2E);
            m_[i] = mn;
            rs[i] = 0.f;
        }
#pragma unroll
        for (int f = 0; f < 4; ++f)
#pragma unroll
            for (int i = 0; i < 4; ++i) {
                float p = exp2f((s[f][i] - m_[i]) * LOG2E);
                s[f][i] = p;
                rs[i] += p;
            }
#pragma unroll
        for (int mk = 1; mk < 16; mk <<= 1)
#pragma unroll
            for (int i = 0; i < 4; ++i) rs[i] += __shfl_xor(rs[i], mk, 64);
#pragma unroll
        for (int i = 0; i < 4; ++i) l_[i] = l_[i] * al[i] + rs[i];
#pragma unroll
        for (int f = 0; f < 8; ++f)
#pragma unroll
            for (int i = 0; i < 4; ++i) o[f][i] *= al[i];

        // ---- P: D layout -> A layout through this wave's LDS buffer ----
#pragma unroll
        for (int f = 0; f < 4; ++f)
#pragma unroll
            for (int i = 0; i < 4; ++i)
                plds[wave][(4 * g + i) * 72 + f * 16 + r] = f2bf(s[f][i]);
        asm volatile("s_waitcnt lgkmcnt(0)" ::: "memory");

        // ---- O += P V ----
#pragma unroll
        for (int kk2 = 0; kk2 < 2; ++kk2) {
            bf16x8 pf = ld8(&plds[wave][r * 72 + kk2 * 32 + 8 * g]);
#pragma unroll
            for (int f = 0; f < 8; ++f) {
                bf16x8 vf = ld8(Vp + (size_t)(f * 16 + r) * S_LEN + k0 + kk2 * 32 + 8 * g);
                o[f] = mfma16(pf, vf, o[f]);
            }
        }
    }

    // ---- cross-wave combine ----
    if (r == 0) {
#pragma unroll
        for (int i = 0; i < 4; ++i) { m_s[wave][4 * g + i] = m_[i]; l_s[wave][4 * g + i] = l_[i]; }
    }
    __syncthreads();

    float scale[4];
#pragma unroll
    for (int i = 0; i < 4; ++i) {
        int row = 4 * g + i;
        float mm = fmaxf(fmaxf(m_s[0][row], m_s[1][row]), fmaxf(m_s[2][row], m_s[3][row]));
        scale[i] = exp2f((m_[i] - mm) * LOG2E); // 0 for no-work waves (m_=-1e30)
    }
    for (int t = threadIdx.x; t < 16 * 128; t += 256) ((float*)o_acc)[t] = 0.f;
    __syncthreads();

    for (int w = 0; w < NW; ++w) {
        if (wave == w) {
#pragma unroll
            for (int f = 0; f < 8; ++f)
#pragma unroll
                for (int i = 0; i < 4; ++i)
                    o_acc[4 * g + i][f * 16 + r] += o[f][i] * scale[i];
        }
        __syncthreads();
    }

    // ---- normalize + coalesced write: thread t -> row t>>4, cols (t&15)*8.. ----
    {
        const int row = threadIdx.x >> 4, c0 = (threadIdx.x & 15) * 8;
        float mm = fmaxf(fmaxf(m_s[0][row], m_s[1][row]), fmaxf(m_s[2][row], m_s[3][row]));
        float ls = 0.f;
#pragma unroll
        for (int w = 0; w < NW; ++w) ls += l_s[w][row] * exp2f((m_s[w][row] - mm) * LOG2E);
        const float invl = 1.0f / ls;
        float* op = out + ((size_t)(b * S_LEN + q0 + row)) * D_OUT + c0;
        float4 v0, v1;
        v0.x = o_acc[row][c0 + 0] * invl; v0.y = o_acc[row][c0 + 1] * invl;
        v0.z = o_acc[row][c0 + 2] * invl; v0.w = o_acc[row][c0 + 3] * invl;
        v1.x = o_acc[row][c0 + 4] * invl; v1.y = o_acc[row][c0 + 5] * invl;
        v1.z = o_acc[row][c0 + 6] * invl; v1.w = o_acc[row][c0 + 7] * invl;
        *reinterpret_cast<float4*>(op) = v0;
        *reinterpret_cast<float4*>(op + 4) = v1;
    }
}

extern "C" void kernel_launch(void* const* d_in, const int* in_sizes, int n_in,
                              void* d_out, int out_size, void* d_ws, size_t ws_size,
                              hipStream_t stream) {
    const float* x  = (const float*)d_in[0];
    const float* Wq = (const float*)d_in[1];
    const float* Wk = (const float*)d_in[2];
    const float* Wv = (const float*)d_in[3];
    float* out = (float*)d_out;

    // workspace layout (bf16 ushorts): Q | K | V^T | W^T  = ~12.6 MiB
    u16* Qb = (u16*)d_ws;
    u16* Kb = Qb + (size_t)M_TOTAL * D_OUT;
    u16* Vt = Kb + (size_t)M_TOTAL * D_OUT;
    u16* Wt = Vt + (size_t)M_TOTAL * D_OUT;

    wt_kernel<<<(3 * D_OUT * D_IN) / 256, 256, 0, stream>>>(Wq, Wk, Wv, Wt);
    qkv_kernel<<<dim3(M_TOTAL / 64, 3), 256, 0, stream>>>(x, Wt, Qb, Kb, Vt);
    attn_kernel<<<dim3(S_LEN / 16, NB), 256, 0, stream>>>(Qb, Kb, Vt, out);
}